// Round 1
// baseline (7688.491 us; speedup 1.0000x reference)
//
#include <hip/hip_runtime.h>
#include <math.h>

// HierarchicalDynamicSlotsSoftMoE — fp32 correctness-first implementation.
// b=4, N=8192, d=1024, K=64, G=128 (BG=512), E1=8, S1=2 (M=16), HID=4096,
// stage2: L=2048 tokens/batch, E2=4, n2=512.

namespace {
constexpr int kD    = 1024;
constexpr int kK    = 64;     // tokens per group
constexpr int kM    = 16;     // E1*S1 slots per group
constexpr int kHid  = 4096;
constexpr int kL    = 2048;   // stage-2 tokens per batch (= stage-2 slot count)
constexpr int kBG   = 512;    // b*G
constexpr float kSqrtD = 32.0f;
}

__device__ __forceinline__ float gelu_exact(float v){
  return 0.5f * v * (1.0f + erff(v * 0.70710678118654752f));
}

// 64x64 tile, 4x4 per-thread microtile, As/Bs are [16][64] in LDS.
__device__ __forceinline__ void tile_mm(const float* __restrict__ As, const float* __restrict__ Bs,
                                        float (&acc)[4][4], int ty, int tx){
  #pragma unroll
  for(int kk=0; kk<16; kk++){
    float4 a = *(const float4*)(As + kk*64 + ty*4);
    float4 b = *(const float4*)(Bs + kk*64 + tx*4);
    acc[0][0]=fmaf(a.x,b.x,acc[0][0]); acc[0][1]=fmaf(a.x,b.y,acc[0][1]);
    acc[0][2]=fmaf(a.x,b.z,acc[0][2]); acc[0][3]=fmaf(a.x,b.w,acc[0][3]);
    acc[1][0]=fmaf(a.y,b.x,acc[1][0]); acc[1][1]=fmaf(a.y,b.y,acc[1][1]);
    acc[1][2]=fmaf(a.y,b.z,acc[1][2]); acc[1][3]=fmaf(a.y,b.w,acc[1][3]);
    acc[2][0]=fmaf(a.z,b.x,acc[2][0]); acc[2][1]=fmaf(a.z,b.y,acc[2][1]);
    acc[2][2]=fmaf(a.z,b.z,acc[2][2]); acc[2][3]=fmaf(a.z,b.w,acc[2][3]);
    acc[3][0]=fmaf(a.w,b.x,acc[3][0]); acc[3][1]=fmaf(a.w,b.y,acc[3][1]);
    acc[3][2]=fmaf(a.w,b.z,acc[3][2]); acc[3][3]=fmaf(a.w,b.w,acc[3][3]);
  }
}

// -------------------- K1a: group mean + gate scalar --------------------
__global__ __launch_bounds__(256) void k_gm_gates(const float* __restrict__ x,
                                                  const float* __restrict__ Wg,
                                                  const float* __restrict__ bgp,
                                                  float* __restrict__ gm,
                                                  float* __restrict__ gates){
  const int bgid = blockIdx.x;
  const int t = threadIdx.x;
  const float* xg = x + (size_t)bgid * kK * kD;
  float4 acc = {0.f,0.f,0.f,0.f};
  for(int k=0;k<kK;k++){
    float4 v = *(const float4*)(xg + (size_t)k*kD + t*4);
    acc.x += v.x; acc.y += v.y; acc.z += v.z; acc.w += v.w;
  }
  const float inv = 1.0f/(float)kK;
  acc.x*=inv; acc.y*=inv; acc.z*=inv; acc.w*=inv;
  *(float4*)(gm + (size_t)bgid*kD + t*4) = acc;
  float4 w = *(const float4*)(Wg + t*4);
  float p = acc.x*w.x + acc.y*w.y + acc.z*w.z + acc.w*w.w;
  __shared__ float red[256];
  red[t] = p; __syncthreads();
  for(int s=128;s>0;s>>=1){ if(t<s) red[t]+=red[t+s]; __syncthreads(); }
  if(t==0){
    float z = red[0] + bgp[0];
    float sg = 1.0f/(1.0f + __expf(-z));
    gates[bgid] = fminf(fmaxf(sg, 0.01f), 1.0f);
  }
}

// -------------------- K1b: per-token 1/max(||x||,eps) --------------------
__global__ __launch_bounds__(256) void k_rownorm(const float* __restrict__ X,
                                                 float* __restrict__ rn){
  const int tok  = blockIdx.x*4 + (threadIdx.x>>6);
  const int lane = threadIdx.x & 63;
  const float* row = X + (size_t)tok * kD;
  float s = 0.f;
  #pragma unroll
  for(int i=0;i<4;i++){
    float4 v = *(const float4*)(row + (i*64+lane)*4);
    s += v.x*v.x + v.y*v.y + v.z*v.z + v.w*v.w;
  }
  #pragma unroll
  for(int o=32;o>0;o>>=1) s += __shfl_xor(s, o);
  if(lane==0) rn[tok] = 1.0f / fmaxf(sqrtf(s), 1e-8f);
}

// -------------------- K3/K9: slot vectors -> folded effective slots ------
// p <- p * gA * gB * kD / max(||p||,eps)   (one wave per slot row)
__global__ __launch_bounds__(256) void k_norm_slots(float* __restrict__ P,
                                                    const float* __restrict__ gA,
                                                    const float* __restrict__ gB){
  const int slot = blockIdx.x*4 + (threadIdx.x>>6);
  const int lane = threadIdx.x & 63;
  float* row = P + (size_t)slot * kD;
  float4 vv[4]; float s = 0.f;
  #pragma unroll
  for(int i=0;i<4;i++){
    vv[i] = *(const float4*)(row + (i*64+lane)*4);
    s += vv[i].x*vv[i].x + vv[i].y*vv[i].y + vv[i].z*vv[i].z + vv[i].w*vv[i].w;
  }
  #pragma unroll
  for(int o=32;o>0;o>>=1) s += __shfl_xor(s, o);
  const float scale = (float)kD / fmaxf(sqrtf(s), 1e-8f);
  #pragma unroll
  for(int i=0;i<4;i++){
    int c = (i*64+lane)*4;
    float4 ga = *(const float4*)(gA + c);
    float4 gb = *(const float4*)(gB + c);
    float4 v = vv[i];
    v.x *= scale*ga.x*gb.x; v.y *= scale*ga.y*gb.y;
    v.z *= scale*ga.z*gb.z; v.w *= scale*ga.w*gb.w;
    *(float4*)(row + c) = v;
  }
}

// -------------------- K2/K8: plain projection GEMM ----------------------
// C(MxN) = A(MxKd) @ B(KdxN).  mode 0: row-major out. mode 1: se2 remap.
__global__ __launch_bounds__(256) void k_gemm_proj(const float* __restrict__ A,
                                                   const float* __restrict__ B,
                                                   float* __restrict__ C,
                                                   int N, int Kd, int mode){
  __shared__ float As[16*64];
  __shared__ float Bs[16*64];
  const int t = threadIdx.x;
  const int tx = t & 15, ty = t >> 4;
  const int r0 = blockIdx.y*64, c0 = blockIdx.x*64;
  const int lar = t>>2, lak = (t&3)*4;
  const int lbk = t>>4, lbn = (t&15)*4;
  const float* Ap = A + (size_t)(r0+lar)*Kd + lak;
  const float* Bp = B + (size_t)lbk*N + c0 + lbn;
  float acc[4][4] = {};
  for(int k0=0;k0<Kd;k0+=16){
    float4 av = *(const float4*)(Ap + k0);
    float4 bv = *(const float4*)(Bp + (size_t)k0*N);
    __syncthreads();
    As[(lak+0)*64+lar]=av.x; As[(lak+1)*64+lar]=av.y;
    As[(lak+2)*64+lar]=av.z; As[(lak+3)*64+lar]=av.w;
    *(float4*)(Bs + lbk*64 + lbn) = bv;
    __syncthreads();
    tile_mm(As, Bs, acc, ty, tx);
  }
  if(mode==0){
    #pragma unroll
    for(int i=0;i<4;i++){
      float4 v = {acc[i][0],acc[i][1],acc[i][2],acc[i][3]};
      *(float4*)(C + (size_t)(r0+ty*4+i)*N + c0+tx*4) = v;
    }
  } else {
    // out[((b*4+e)*512 + (r&511))*1024 + dd]
    const int bb = r0 >> 9, e = c0 >> 10;
    const size_t base = ((size_t)(bb*4+e)*512 + (r0&511))*(size_t)kD + (c0&1023);
    #pragma unroll
    for(int i=0;i<4;i++){
      float4 v = {acc[i][0],acc[i][1],acc[i][2],acc[i][3]};
      *(float4*)(C + base + (size_t)(ty*4+i)*kD + tx*4) = v;
    }
  }
}

// -------------------- K4: per-group MoE (logits+softmax+slot mix) -------
__global__ __launch_bounds__(256) void k_group_moe(const float* __restrict__ x,
                                                   const float* __restrict__ se1,
                                                   const float* __restrict__ rn1,
                                                   float* __restrict__ combine,
                                                   float* __restrict__ slots1){
  const int bgid = blockIdx.x;
  const int t = threadIdx.x;
  const float* xg = x   + (size_t)bgid * kK * kD;
  const float* se = se1 + (size_t)bgid * kM * kD;
  __shared__ float lx[64*132];
  __shared__ float lse[16*132];
  __shared__ float lg[64*17];
  __shared__ float lrn[64];
  if(t < 64) lrn[t] = rn1[bgid*64 + t];

  float acc[4] = {0.f,0.f,0.f,0.f};
  const int krow = t >> 2;
  const int mg   = (t & 3) * 4;
  for(int ch=0; ch<8; ch++){
    __syncthreads();
    #pragma unroll
    for(int i=0;i<8;i++){
      int idx = t + i*256;
      int row = idx >> 5, c4 = (idx & 31)*4;
      *(float4*)(lx + row*132 + c4) = *(const float4*)(xg + (size_t)row*kD + ch*128 + c4);
    }
    #pragma unroll
    for(int i=0;i<2;i++){
      int idx = t + i*256;
      int row = idx >> 5, c4 = (idx & 31)*4;
      *(float4*)(lse + row*132 + c4) = *(const float4*)(se + (size_t)row*kD + ch*128 + c4);
    }
    __syncthreads();
    for(int dd=0; dd<128; dd++){
      float xv = lx[krow*132 + dd];
      acc[0] = fmaf(xv, lse[(mg+0)*132 + dd], acc[0]);
      acc[1] = fmaf(xv, lse[(mg+1)*132 + dd], acc[1]);
      acc[2] = fmaf(xv, lse[(mg+2)*132 + dd], acc[2]);
      acc[3] = fmaf(xv, lse[(mg+3)*132 + dd], acc[3]);
    }
  }
  __syncthreads();
  lg[krow*17 + mg+0] = acc[0]; lg[krow*17 + mg+1] = acc[1];
  lg[krow*17 + mg+2] = acc[2]; lg[krow*17 + mg+3] = acc[3];
  __syncthreads();
  if(t < 64){
    const float rnv = lrn[t];
    float vals[16]; float m = -1e30f;
    #pragma unroll
    for(int j=0;j<16;j++){ float v = lg[t*17+j]*rnv; vals[j]=v; m = fmaxf(m, v); }
    float s = 0.f;
    #pragma unroll
    for(int j=0;j<16;j++){ vals[j] = __expf(vals[j]-m); s += vals[j]; }
    const float si = 1.0f/s;
    #pragma unroll
    for(int j=0;j<16;j++) lg[t*17+j] = vals[j]*si;
  }
  __syncthreads();
  { // write combine (b,G,K,M): element t*4+j
    const int kk = t>>2, mm = (t&3)*4;
    float4 cv = {lg[kk*17+mm], lg[kk*17+mm+1], lg[kk*17+mm+2], lg[kk*17+mm+3]};
    *(float4*)(combine + (size_t)bgid*kK*kM + t*4) = cv;
  }
  // slots[m][:] = sum_k x[k][:] * combine[k][m]
  const int dj = (t & 31) * 4;
  const int mp = t >> 5;           // handles m = 2*mp, 2*mp+1
  for(int ch=0; ch<8; ch++){
    __syncthreads();
    #pragma unroll
    for(int i=0;i<8;i++){
      int idx = t + i*256;
      int row = idx >> 5, c4 = (idx & 31)*4;
      *(float4*)(lx + row*132 + c4) = *(const float4*)(xg + (size_t)row*kD + ch*128 + c4);
    }
    __syncthreads();
    float4 a0 = {0.f,0.f,0.f,0.f}, a1 = {0.f,0.f,0.f,0.f};
    for(int kk=0; kk<64; kk++){
      float c0v = lg[kk*17 + 2*mp];
      float c1v = lg[kk*17 + 2*mp + 1];
      float4 xv = *(const float4*)(lx + kk*132 + dj);
      a0.x=fmaf(xv.x,c0v,a0.x); a0.y=fmaf(xv.y,c0v,a0.y); a0.z=fmaf(xv.z,c0v,a0.z); a0.w=fmaf(xv.w,c0v,a0.w);
      a1.x=fmaf(xv.x,c1v,a1.x); a1.y=fmaf(xv.y,c1v,a1.y); a1.z=fmaf(xv.z,c1v,a1.z); a1.w=fmaf(xv.w,c1v,a1.w);
    }
    float* sb = slots1 + (size_t)bgid*kM*kD + ch*128 + dj;
    *(float4*)(sb + (size_t)(2*mp  )*kD) = a0;
    *(float4*)(sb + (size_t)(2*mp+1)*kD) = a1;
  }
}

// -------------------- K5/K14: expert FFN up-proj + GELU -----------------
// mode 1 (stage1): row r -> slots1[(r>>1)*16 + e*2 + (r&1)]
// mode 2 (stage2): row r -> slots2[(r>>9)*2048 + e*512 + (r&511)]
__global__ __launch_bounds__(256) void k_gemm_ffn_a(const float* __restrict__ S,
                                                    const float* __restrict__ W1,
                                                    const float* __restrict__ b1,
                                                    float* __restrict__ H,
                                                    int e, int mode){
  __shared__ float As[16*64];
  __shared__ float Bs[16*64];
  const int t = threadIdx.x;
  const int tx = t & 15, ty = t >> 4;
  const int r0 = blockIdx.y*64, c0 = blockIdx.x*64;
  const int lar = t>>2, lak = (t&3)*4;
  const int lbk = t>>4, lbn = (t&15)*4;
  const int r = r0 + lar;
  const size_t arow = (mode==1)
      ? (size_t)((r>>1)*16 + e*2 + (r&1)) * kD
      : (size_t)((r>>9)*2048 + e*512 + (r&511)) * kD;
  const float* Ap = S + arow + lak;
  const float* Bp = W1 + (size_t)e*kD*kHid + (size_t)lbk*kHid + c0 + lbn;
  float acc[4][4] = {};
  for(int k0=0;k0<kD;k0+=16){
    float4 av = *(const float4*)(Ap + k0);
    float4 bv = *(const float4*)(Bp + (size_t)k0*kHid);
    __syncthreads();
    As[(lak+0)*64+lar]=av.x; As[(lak+1)*64+lar]=av.y;
    As[(lak+2)*64+lar]=av.z; As[(lak+3)*64+lar]=av.w;
    *(float4*)(Bs + lbk*64 + lbn) = bv;
    __syncthreads();
    tile_mm(As, Bs, acc, ty, tx);
  }
  const float* bb = b1 + (size_t)e*kHid + c0 + tx*4;
  #pragma unroll
  for(int i=0;i<4;i++){
    float4 v;
    v.x = gelu_exact(acc[i][0] + bb[0]);
    v.y = gelu_exact(acc[i][1] + bb[1]);
    v.z = gelu_exact(acc[i][2] + bb[2]);
    v.w = gelu_exact(acc[i][3] + bb[3]);
    *(float4*)(H + (size_t)(r0+ty*4+i)*kHid + c0 + tx*4) = v;
  }
}

// -------------------- K6/K15: expert FFN down-proj ----------------------
// mode 1: out = seq token (r>>1)*16+e*2+(r&1), scale = eg[e]*gates[r>>1]
// mode 2: out = o2 row (r>>9)*2048 + e*512 + (r&511), scale = 1
__global__ __launch_bounds__(256) void k_gemm_ffn_b(const float* __restrict__ H,
                                                    const float* __restrict__ W2,
                                                    const float* __restrict__ b2,
                                                    const float* __restrict__ eg,
                                                    const float* __restrict__ gates,
                                                    float* __restrict__ outp,
                                                    int e, int mode){
  __shared__ float As[16*64];
  __shared__ float Bs[16*64];
  const int t = threadIdx.x;
  const int tx = t & 15, ty = t >> 4;
  const int r0 = blockIdx.y*64, c0 = blockIdx.x*64;
  const int lar = t>>2, lak = (t&3)*4;
  const int lbk = t>>4, lbn = (t&15)*4;
  const float* Ap = H + (size_t)(r0+lar)*kHid + lak;
  const float* Bp = W2 + (size_t)e*kHid*kD + (size_t)lbk*kD + c0 + lbn;
  float acc[4][4] = {};
  for(int k0=0;k0<kHid;k0+=16){
    float4 av = *(const float4*)(Ap + k0);
    float4 bv = *(const float4*)(Bp + (size_t)k0*kD);
    __syncthreads();
    As[(lak+0)*64+lar]=av.x; As[(lak+1)*64+lar]=av.y;
    As[(lak+2)*64+lar]=av.z; As[(lak+3)*64+lar]=av.w;
    *(float4*)(Bs + lbk*64 + lbn) = bv;
    __syncthreads();
    tile_mm(As, Bs, acc, ty, tx);
  }
  const float* bp = b2 + (size_t)e*kD + c0 + tx*4;
  #pragma unroll
  for(int i=0;i<4;i++){
    const int r = r0 + ty*4 + i;
    float4 v;
    if(mode==1){
      const float scale = eg[e] * gates[r>>1];
      const size_t tok = (size_t)((r>>1)*16 + e*2 + (r&1));
      v.x = (acc[i][0]+bp[0])*scale; v.y = (acc[i][1]+bp[1])*scale;
      v.z = (acc[i][2]+bp[2])*scale; v.w = (acc[i][3]+bp[3])*scale;
      *(float4*)(outp + tok*kD + c0 + tx*4) = v;
    } else {
      const size_t ro = (size_t)((r>>9)*2048 + e*512 + (r&511));
      v.x = acc[i][0]+bp[0]; v.y = acc[i][1]+bp[1];
      v.z = acc[i][2]+bp[2]; v.w = acc[i][3]+bp[3];
      *(float4*)(outp + ro*kD + c0 + tx*4) = v;
    }
  }
}

// -------------------- K7: stage-2 token norms + consecutive mean --------
__global__ __launch_bounds__(256) void k_stage2_stats(const float* __restrict__ seq,
                                                      const float* __restrict__ gamma2,
                                                      float* __restrict__ rn2,
                                                      float* __restrict__ cmean){
  const int grp = blockIdx.x;           // b*512 + n2
  const int t = threadIdx.x, w = t>>6, lane = t&63;
  const float* base = seq + (size_t)grp*4*kD;
  __shared__ float lrn[4];
  {
    const float* row = base + (size_t)w*kD;
    float s = 0.f;
    #pragma unroll
    for(int i=0;i<4;i++){
      float4 v = *(const float4*)(row + (i*64+lane)*4);
      s += v.x*v.x + v.y*v.y + v.z*v.z + v.w*v.w;
    }
    #pragma unroll
    for(int o=32;o>0;o>>=1) s += __shfl_xor(s, o);
    if(lane==0){
      float r = 1.0f / fmaxf(sqrtf(s), 1e-8f);
      lrn[w] = r;
      rn2[grp*4 + w] = r;
    }
  }
  __syncthreads();
  const float r0=lrn[0], r1=lrn[1], r2=lrn[2], r3=lrn[3];
  const int c = t*4;
  float4 v0 = *(const float4*)(base + c);
  float4 v1 = *(const float4*)(base + kD + c);
  float4 v2 = *(const float4*)(base + 2*kD + c);
  float4 v3 = *(const float4*)(base + 3*kD + c);
  float4 g  = *(const float4*)(gamma2 + c);
  float4 o;
  o.x = (v0.x*r0 + v1.x*r1 + v2.x*r2 + v3.x*r3) * 8.0f * g.x;  // sqrt(D)/4 = 8
  o.y = (v0.y*r0 + v1.y*r1 + v2.y*r2 + v3.y*r3) * 8.0f * g.y;
  o.z = (v0.z*r0 + v1.z*r1 + v2.z*r2 + v3.z*r3) * 8.0f * g.z;
  o.w = (v0.w*r0 + v1.w*r1 + v2.w*r2 + v3.w*r3) * 8.0f * g.w;
  *(float4*)(cmean + (size_t)grp*kD + c) = o;
}

// -------------------- K10: logits2 = rn2 * (seq @ se2_eff^T) ------------
__global__ __launch_bounds__(256) void k_gemm_logits2(const float* __restrict__ seq,
                                                      const float* __restrict__ se2,
                                                      const float* __restrict__ rn2,
                                                      float* __restrict__ L2){
  const int b = blockIdx.z;
  __shared__ float As[16*64];
  __shared__ float Bs[16*64];
  const int t = threadIdx.x;
  const int tx = t & 15, ty = t >> 4;
  const int r0 = blockIdx.y*64, c0 = blockIdx.x*64;
  const int lar = t>>2, lak = (t&3)*4;
  const float* Ap = seq + (size_t)b*kL*kD + (size_t)(r0+lar)*kD + lak;
  const float* Bp = se2 + (size_t)b*kL*kD + (size_t)(c0+lar)*kD + lak;
  float acc[4][4] = {};
  for(int k0=0;k0<kD;k0+=16){
    float4 av = *(const float4*)(Ap + k0);
    float4 bv = *(const float4*)(Bp + k0);
    __syncthreads();
    As[(lak+0)*64+lar]=av.x; As[(lak+1)*64+lar]=av.y;
    As[(lak+2)*64+lar]=av.z; As[(lak+3)*64+lar]=av.w;
    Bs[(lak+0)*64+lar]=bv.x; Bs[(lak+1)*64+lar]=bv.y;
    Bs[(lak+2)*64+lar]=bv.z; Bs[(lak+3)*64+lar]=bv.w;
    __syncthreads();
    tile_mm(As, Bs, acc, ty, tx);
  }
  #pragma unroll
  for(int i=0;i<4;i++){
    const int r = r0 + ty*4 + i;
    const float rnv = rn2[b*kL + r];
    float4 v = {acc[i][0]*rnv, acc[i][1]*rnv, acc[i][2]*rnv, acc[i][3]*rnv};
    *(float4*)(L2 + (size_t)b*kL*kL + (size_t)r*kL + c0 + tx*4) = v;
  }
}

// -------------------- K11: column (dispatch) softmax stats --------------
__global__ __launch_bounds__(256) void k_colstats(const float* __restrict__ L2,
                                                  float* __restrict__ cmax,
                                                  float* __restrict__ csum){
  const int b = blockIdx.z;
  const int c0 = blockIdx.x*64;
  const int t = threadIdx.x;
  const int col = c0 + (t & 63);
  const int rr = t >> 6;
  const float* Lb = L2 + (size_t)b*kL*kL;
  float m = -1e30f, s = 0.f;
  for(int r=rr; r<kL; r+=4){
    float v = Lb[(size_t)r*kL + col];
    if(v > m){ s = s*__expf(m-v) + 1.0f; m = v; }
    else     { s += __expf(v-m); }
  }
  __shared__ float lm[4][64], ls[4][64];
  lm[rr][t&63] = m; ls[rr][t&63] = s;
  __syncthreads();
  if(t < 64){
    float M = lm[0][t], S = ls[0][t];
    #pragma unroll
    for(int q=1;q<4;q++){
      float m2 = lm[q][t], s2 = ls[q][t];
      if(m2 > M){ S = S*__expf(M-m2) + s2; M = m2; }
      else      { S += s2*__expf(m2-M); }
    }
    cmax[b*kL + c0 + t] = M;
    csum[b*kL + c0 + t] = S;
  }
}

// -------------------- K13: row (combine2) softmax stats -----------------
__global__ __launch_bounds__(256) void k_rowstats(const float* __restrict__ L2,
                                                  float* __restrict__ rmax,
                                                  float* __restrict__ rsum){
  const int b = blockIdx.z, n = blockIdx.x, t = threadIdx.x;
  const float* row = L2 + ((size_t)b*kL + n)*kL;
  float4 a = *(const float4*)(row + t*8);
  float4 c = *(const float4*)(row + t*8 + 4);
  float lm = fmaxf(fmaxf(fmaxf(a.x,a.y),fmaxf(a.z,a.w)),
                   fmaxf(fmaxf(c.x,c.y),fmaxf(c.z,c.w)));
  __shared__ float red[256];
  red[t] = lm; __syncthreads();
  for(int s=128;s>0;s>>=1){ if(t<s) red[t]=fmaxf(red[t],red[t+s]); __syncthreads(); }
  const float M = red[0];
  __syncthreads();
  float ls = __expf(a.x-M)+__expf(a.y-M)+__expf(a.z-M)+__expf(a.w-M)
           + __expf(c.x-M)+__expf(c.y-M)+__expf(c.z-M)+__expf(c.w-M);
  red[t] = ls; __syncthreads();
  for(int s=128;s>0;s>>=1){ if(t<s) red[t]+=red[t+s]; __syncthreads(); }
  if(t==0){ rmax[b*kL+n] = M; rsum[b*kL+n] = red[0]; }
}

// -------------------- K12: slots2 = dispatch^T @ xs ---------------------
__global__ __launch_bounds__(256) void k_gemm_slots2(const float* __restrict__ L2,
                                                     const float* __restrict__ seq,
                                                     const float* __restrict__ rn2,
                                                     const float* __restrict__ gamma2,
                                                     const float* __restrict__ cmax,
                                                     const float* __restrict__ csum,
                                                     float* __restrict__ slots2){
  const int b = blockIdx.z;
  const int t = threadIdx.x;
  const int tx = t & 15, ty = t >> 4;
  const int r0 = blockIdx.y*64;   // es block
  const int c0 = blockIdx.x*64;   // d block
  __shared__ float As[16*64];
  __shared__ float Bs[16*64];
  __shared__ float cm_l[64], csi_l[64], g2_l[64];
  if(t < 64){
    cm_l[t]  = cmax[b*kL + r0 + t];
    csi_l[t] = 1.0f / csum[b*kL + r0 + t];
    g2_l[t]  = gamma2[c0 + t] * kSqrtD;
  }
  __syncthreads();
  const int lk = t>>4, l4 = (t&15)*4;
  const float* Lp = L2  + (size_t)b*kL*kL + (size_t)lk*kL + r0 + l4;
  const float* Sp = seq + (size_t)b*kL*kD + (size_t)lk*kD + c0 + l4;
  const float* rp = rn2 + b*kL + lk;
  float acc[4][4] = {};
  for(int n0=0;n0<kL;n0+=16){
    float4 lv = *(const float4*)(Lp + (size_t)n0*kL);
    float4 sv = *(const float4*)(Sp + (size_t)n0*kD);
    const float rnv = rp[n0];
    __syncthreads();
    As[lk*64 + l4+0] = __expf(lv.x - cm_l[l4+0]);
    As[lk*64 + l4+1] = __expf(lv.y - cm_l[l4+1]);
    As[lk*64 + l4+2] = __expf(lv.z - cm_l[l4+2]);
    As[lk*64 + l4+3] = __expf(lv.w - cm_l[l4+3]);
    float4 w;
    w.x = sv.x*rnv*g2_l[l4+0]; w.y = sv.y*rnv*g2_l[l4+1];
    w.z = sv.z*rnv*g2_l[l4+2]; w.w = sv.w*rnv*g2_l[l4+3];
    *(float4*)(Bs + lk*64 + l4) = w;
    __syncthreads();
    tile_mm(As, Bs, acc, ty, tx);
  }
  #pragma unroll
  for(int i=0;i<4;i++){
    const float s = csi_l[ty*4+i];
    float4 v = {acc[i][0]*s, acc[i][1]*s, acc[i][2]*s, acc[i][3]*s};
    *(float4*)(slots2 + (size_t)b*kL*kD + (size_t)(r0+ty*4+i)*kD + c0 + tx*4) = v;
  }
}

// -------------------- K16: out2 = comb2 @ o2 ----------------------------
__global__ __launch_bounds__(256) void k_gemm_out2(const float* __restrict__ L2,
                                                   const float* __restrict__ O,
                                                   const float* __restrict__ rmax,
                                                   const float* __restrict__ rsum,
                                                   float* __restrict__ out2){
  const int b = blockIdx.z;
  const int t = threadIdx.x;
  const int tx = t & 15, ty = t >> 4;
  const int r0 = blockIdx.y*64;   // token block
  const int c0 = blockIdx.x*64;   // d block
  __shared__ float As[16*64];
  __shared__ float Bs[16*64];
  __shared__ float rm_l[64], rsi_l[64];
  if(t < 64){
    rm_l[t]  = rmax[b*kL + r0 + t];
    rsi_l[t] = 1.0f / rsum[b*kL + r0 + t];
  }
  __syncthreads();
  const int lar = t>>2, lak = (t&3)*4;
  const int lbk = t>>4, lbn = (t&15)*4;
  const float* Lp = L2 + (size_t)b*kL*kL + (size_t)(r0+lar)*kL + lak;
  const float* Op = O  + (size_t)b*kL*kD + (size_t)lbk*kD + c0 + lbn;
  float acc[4][4] = {};
  for(int k0=0;k0<kL;k0+=16){
    float4 lv = *(const float4*)(Lp + k0);
    float4 bv = *(const float4*)(Op + (size_t)k0*kD);
    __syncthreads();
    const float rm = rm_l[lar];
    As[(lak+0)*64+lar] = __expf(lv.x - rm);
    As[(lak+1)*64+lar] = __expf(lv.y - rm);
    As[(lak+2)*64+lar] = __expf(lv.z - rm);
    As[(lak+3)*64+lar] = __expf(lv.w - rm);
    *(float4*)(Bs + lbk*64 + lbn) = bv;
    __syncthreads();
    tile_mm(As, Bs, acc, ty, tx);
  }
  #pragma unroll
  for(int i=0;i<4;i++){
    const float s = rsi_l[ty*4+i];
    float4 v = {acc[i][0]*s, acc[i][1]*s, acc[i][2]*s, acc[i][3]*s};
    *(float4*)(out2 + (size_t)b*kL*kD + (size_t)(r0+ty*4+i)*kD + c0 + tx*4) = v;
  }
}

// -------------------- K17: final recombine ------------------------------
__global__ __launch_bounds__(256) void k_final(const float* __restrict__ out2,
                                               const float* __restrict__ combine,
                                               float* __restrict__ outp){
  const int bgid = blockIdx.x;
  const int t = threadIdx.x;
  __shared__ float lc[64*17];
  __shared__ float lo[16*132];
  {
    const int kk = t>>2, mm = (t&3)*4;
    float4 v = *(const float4*)(combine + (size_t)bgid*kK*kM + t*4);
    lc[kk*17+mm]=v.x; lc[kk*17+mm+1]=v.y; lc[kk*17+mm+2]=v.z; lc[kk*17+mm+3]=v.w;
  }
  const float* o = out2 + (size_t)bgid * kM * kD;   // out2 viewed (b,G,16,d)
  float* dst = outp + (size_t)bgid * kK * kD;
  const int dj = (t & 31) * 4;
  const int k0 = (t >> 5) * 8;
  for(int ch=0; ch<8; ch++){
    __syncthreads();
    #pragma unroll
    for(int i=0;i<2;i++){
      int idx = t + i*256;
      int row = idx >> 5, c4 = (idx & 31)*4;
      *(float4*)(lo + row*132 + c4) = *(const float4*)(o + (size_t)row*kD + ch*128 + c4);
    }
    __syncthreads();
    #pragma unroll
    for(int kq=0;kq<8;kq++){
      const int kk = k0 + kq;
      float4 a = {0.f,0.f,0.f,0.f};
      #pragma unroll
      for(int m=0;m<16;m++){
        const float c = lc[kk*17 + m];
        float4 ov = *(const float4*)(lo + m*132 + dj);
        a.x = fmaf(c, ov.x, a.x); a.y = fmaf(c, ov.y, a.y);
        a.z = fmaf(c, ov.z, a.z); a.w = fmaf(c, ov.w, a.w);
      }
      *(float4*)(dst + (size_t)kk*kD + ch*128 + dj) = a;
    }
  }
}

// ------------------------------------------------------------------------
extern "C" void kernel_launch(void* const* d_in, const int* in_sizes, int n_in,
                              void* d_out, int out_size, void* d_ws, size_t ws_size,
                              hipStream_t stream) {
  (void)in_sizes; (void)n_in; (void)out_size; (void)ws_size;
  const float* x           = (const float*)d_in[0];
  const float* gamma1      = (const float*)d_in[1];
  const float* W_slot1     = (const float*)d_in[2];
  const float* gamma_slot1 = (const float*)d_in[3];
  const float* W1_first    = (const float*)d_in[4];
  const float* b1_first    = (const float*)d_in[5];
  const float* W2_first    = (const float*)d_in[6];
  const float* b2_first    = (const float*)d_in[7];
  const float* expert_gates= (const float*)d_in[8];
  const float* Wg          = (const float*)d_in[9];
  const float* bgp         = (const float*)d_in[10];
  const float* gamma2      = (const float*)d_in[11];
  const float* W_slot2     = (const float*)d_in[12];
  const float* gamma_slot2 = (const float*)d_in[13];
  const float* W1_second   = (const float*)d_in[14];
  const float* b1_second   = (const float*)d_in[15];
  const float* W2_second   = (const float*)d_in[16];
  const float* b2_second   = (const float*)d_in[17];

  size_t off = 0;
  auto alloc = [&](size_t elems) -> float* {
    float* p = (float*)((char*)d_ws + off);
    off += ((elems*sizeof(float) + 255) / 256) * 256;
    return p;
  };
  float* gm      = alloc(512*1024);
  float* gates   = alloc(512);
  float* rn1     = alloc(32768);
  float* se1     = alloc(8388608);      // (bg,16,1024); later reused as o2
  float* combine = alloc(524288);       // (bg,64,16)
  float* slots1  = alloc(8388608);      // (bg,16,1024); later reused as slots2
  float* seqb    = alloc(8388608);      // (b,2048,1024); later reused as out2
  float* rn2     = alloc(8192);
  float* cmean   = alloc(2097152);      // (b*512,1024)
  float* se2     = alloc(8388608);      // (b,4,512,1024); doubles as FFN hidden buf
  float* logits2 = alloc(16777216);     // (b,2048,2048)
  float* cmax    = alloc(8192);
  float* csum    = alloc(8192);
  float* rmax    = alloc(8192);
  float* rsum    = alloc(8192);
  float* hbuf   = se2;      // FFN hidden (max 2048x4096) — dead/alive windows disjoint
  float* slots2 = slots1;
  float* o2     = se1;
  float* out2   = seqb;

  const dim3 blk(256);

  // ---- stage 1 ----
  k_gm_gates<<<512, blk, 0, stream>>>(x, Wg, bgp, gm, gates);
  k_rownorm<<<8192, blk, 0, stream>>>(x, rn1);
  k_gemm_proj<<<dim3(256, 8), blk, 0, stream>>>(gm, W_slot1, se1, 16384, 1024, 0);
  k_norm_slots<<<2048, blk, 0, stream>>>(se1, gamma1, gamma_slot1);
  k_group_moe<<<512, blk, 0, stream>>>(x, se1, rn1, combine, slots1);
  for(int e=0;e<8;e++){
    k_gemm_ffn_a<<<dim3(64, 16), blk, 0, stream>>>(slots1, W1_first, b1_first, hbuf, e, 1);
    k_gemm_ffn_b<<<dim3(16, 16), blk, 0, stream>>>(hbuf, W2_first, b2_first, expert_gates, gates, seqb, e, 1);
  }
  // ---- stage 2 ----
  k_stage2_stats<<<2048, blk, 0, stream>>>(seqb, gamma2, rn2, cmean);
  k_gemm_proj<<<dim3(64, 32), blk, 0, stream>>>(cmean, W_slot2, se2, 4096, 1024, 1);
  k_norm_slots<<<2048, blk, 0, stream>>>(se2, gamma2, gamma_slot2);
  k_gemm_logits2<<<dim3(32, 32, 4), blk, 0, stream>>>(seqb, se2, rn2, logits2);
  k_colstats<<<dim3(32, 1, 4), blk, 0, stream>>>(logits2, cmax, csum);
  k_rowstats<<<dim3(2048, 1, 4), blk, 0, stream>>>(logits2, rmax, rsum);
  k_gemm_slots2<<<dim3(16, 32, 4), blk, 0, stream>>>(logits2, seqb, rn2, gamma2, cmax, csum, slots2);
  for(int e=0;e<4;e++){
    k_gemm_ffn_a<<<dim3(64, 32), blk, 0, stream>>>(slots2, W1_second, b1_second, hbuf, e, 2);
    k_gemm_ffn_b<<<dim3(16, 32), blk, 0, stream>>>(hbuf, W2_second, b2_second, nullptr, nullptr, o2, e, 2);
  }
  k_gemm_out2<<<dim3(16, 32, 4), blk, 0, stream>>>(logits2, o2, rmax, rsum, out2);
  k_final<<<512, blk, 0, stream>>>(out2, combine, (float*)d_out);
}